// Round 9
// baseline (209.661 us; speedup 1.0000x reference)
//
#include <hip/hip_runtime.h>
#include <hip/hip_fp16.h>
#include <hip/hip_bf16.h>

typedef short bf16x8 __attribute__((ext_vector_type(8)));
typedef float f32x4 __attribute__((ext_vector_type(4)));
typedef _Float16 f16x2 __attribute__((ext_vector_type(2)));

#define LGKM_FENCE() asm volatile("s_waitcnt lgkmcnt(0)" ::: "memory")

static __device__ __forceinline__ f16x2 as_f16x2(uint v) {
  union { uint u; f16x2 h; } c; c.u = v; return c.h;
}

// dot of two half2 words accumulated into f32
static __device__ __forceinline__ float dot2acc(uint a, uint b, float c) {
#if __has_builtin(__builtin_amdgcn_fdot2)
  return __builtin_amdgcn_fdot2(as_f16x2(a), as_f16x2(b), c, false);
#else
  float2 af = __half22float2(*(const __half2*)&a);
  float2 bf = __half22float2(*(const __half2*)&b);
  return fmaf(af.x, bf.x, fmaf(af.y, bf.y, c));
#endif
}

// ---------------------------------------------------------------------------
// K1: per-node log_map (bf16 out) + gate softmax; tail blocks transpose W.
// ---------------------------------------------------------------------------
__global__ __launch_bounds__(256) void k_tangent_gate(
    const float* __restrict__ x, const float* __restrict__ Wg,
    const float* __restrict__ bg, __hip_bfloat16* __restrict__ xtb,
    float* __restrict__ gate, const float* __restrict__ Wp,
    __hip_bfloat16* __restrict__ Wt, int N) {
  int tb = (N + 3) >> 2;
  if ((int)blockIdx.x >= tb) {
    int idx = (blockIdx.x - tb) * 256 + threadIdx.x;
    if (idx < 512 * 128) {
      int n = idx >> 7, k = idx & 127;
      Wt[idx] = __float2bfloat16(Wp[(size_t)k * 512 + n]);
    }
    return;
  }
  int wid = (blockIdx.x * blockDim.x + threadIdx.x) >> 6;
  int lane = threadIdx.x & 63;
  if (wid >= N) return;

  const float* xr = x + (size_t)wid * 128;
  float2 xv = *(const float2*)(xr + lane * 2);
  xv.x = fminf(fmaxf(xv.x, -10000.f), 10000.f);
  xv.y = fminf(fmaxf(xv.y, -10000.f), 10000.f);

  float p = xv.x * xv.x + xv.y * xv.y;
  if (lane == 0) p -= 2.f * xv.x * xv.x;
  #pragma unroll
  for (int s = 32; s; s >>= 1) p += __shfl_xor(p, s);
  float x0 = __shfl(xv.x, 0);

  float denom = sqrtf(fmaxf(fabsf(p), 1e-12f));
  float cosd = fmaxf(x0 / denom, 1.0f + 1e-6f);
  float t = cosd - 1.0f;
  float coef = (t < 1e-3f)
      ? 1.0f - t * (1.f / 3.f) + t * t * (2.f / 15.f)
      : acoshf(cosd) * rsqrtf(t * (2.f + t));

  float2 o;
  o.x = coef * ((lane == 0) ? 2.0f * xv.x : xv.x);
  o.y = coef * xv.y;
  __hip_bfloat162 hb = __float22bfloat162_rn(make_float2(o.x, o.y));
  *(__hip_bfloat162*)(xtb + (size_t)wid * 128 + lane * 2) = hb;

  const float4 w0 = *(const float4*)(Wg + (size_t)(lane * 2) * 4);
  const float4 w1 = *(const float4*)(Wg + (size_t)(lane * 2 + 1) * 4);
  float g0 = o.x * w0.x + o.y * w1.x;
  float g1 = o.x * w0.y + o.y * w1.y;
  float g2 = o.x * w0.z + o.y * w1.z;
  float g3 = o.x * w0.w + o.y * w1.w;
  #pragma unroll
  for (int s = 32; s; s >>= 1) {
    g0 += __shfl_xor(g0, s); g1 += __shfl_xor(g1, s);
    g2 += __shfl_xor(g2, s); g3 += __shfl_xor(g3, s);
  }
  g0 += bg[0]; g1 += bg[1]; g2 += bg[2]; g3 += bg[3];
  float m = fmaxf(fmaxf(g0, g1), fmaxf(g2, g3));
  float e0 = expf(g0 - m), e1 = expf(g1 - m), e2 = expf(g2 - m), e3 = expf(g3 - m);
  float z = e0 + e1 + e2 + e3;
  if (lane == 0)
    *(float4*)(gate + (size_t)wid * 4) = make_float4(e0 / z, e1 / z, e2 / z, e3 / z);
}

// ---------------------------------------------------------------------------
// K2: u_hat via bf16 MFMA; gate+bias fused epilogue; f16 output.
// ---------------------------------------------------------------------------
#define BM 64
__global__ __launch_bounds__(256) void k_uhat_mfma(
    const short* __restrict__ xtb, const float* __restrict__ gate,
    const short* __restrict__ Wt, const float* __restrict__ bp,
    __half* __restrict__ uh, int N) {
  __shared__ short sA[BM][136];
  __shared__ short sB[128][136];
  int tid = threadIdx.x;
  int lane = tid & 63;
  int w = tid >> 6;
  int m0 = blockIdx.x * BM;

  #pragma unroll
  for (int it = 0; it < 4; ++it) {
    int idx = it * 256 + tid;
    int r = idx >> 4, c = idx & 15;
    int4 v = make_int4(0, 0, 0, 0);
    if (m0 + r < N) v = *(const int4*)(xtb + (((size_t)(m0 + r)) << 7) + c * 8);
    *(int4*)(&sA[r][c * 8]) = v;
  }

  int mr = w * 16;
  int ri = lane & 15;
  int kg = lane >> 4;
  int rbase = m0 + mr + kg * 4;

  float fin[8][4];
  #pragma unroll
  for (int nt = 0; nt < 8; ++nt)
    #pragma unroll
    for (int q = 0; q < 4; ++q) fin[nt][q] = 0.f;

  for (int p = 0; p < 4; ++p) {
    __syncthreads();
    #pragma unroll
    for (int it = 0; it < 8; ++it) {
      int idx = it * 256 + tid;
      int r = idx >> 4, c = idx & 15;
      int4 v = *(const int4*)(Wt + (((size_t)p * 128 + r) << 7) + c * 8);
      *(int4*)(&sB[r][c * 8]) = v;
    }
    __syncthreads();

    bf16x8 af[4];
    #pragma unroll
    for (int ks = 0; ks < 4; ++ks)
      af[ks] = *(const bf16x8*)(&sA[mr + ri][ks * 32 + kg * 8]);

    #pragma unroll
    for (int nt = 0; nt < 8; ++nt) {
      f32x4 acc = {0.f, 0.f, 0.f, 0.f};
      #pragma unroll
      for (int ks = 0; ks < 4; ++ks) {
        bf16x8 bf = *(const bf16x8*)(&sB[nt * 16 + ri][ks * 32 + kg * 8]);
        acc = __builtin_amdgcn_mfma_f32_16x16x32_bf16(af[ks], bf, acc, 0, 0, 0);
      }
      float bpv = bp[p * 128 + nt * 16 + ri];
      #pragma unroll
      for (int q = 0; q < 4; ++q) {
        int rm = rbase + q;
        float g = (rm < N) ? gate[(size_t)rm * 4 + p] : 0.f;
        fin[nt][q] += g * (acc[q] + bpv);
      }
    }
  }
  #pragma unroll
  for (int nt = 0; nt < 8; ++nt) {
    int cn = nt * 16 + ri;
    #pragma unroll
    for (int q = 0; q < 4; ++q) {
      int rm = rbase + q;
      if (rm < N) uh[(size_t)rm * 128 + cn] = __float2half_rn(fin[nt][q]);
    }
  }
}

// ---------------------------------------------------------------------------
// CSR-by-col: histogram + hierarchical scan + scatter
// ---------------------------------------------------------------------------
__global__ void k_hist(const int* __restrict__ col, int* __restrict__ deg, int E) {
  int e = blockIdx.x * blockDim.x + threadIdx.x;
  if (e < E) atomicAdd(&deg[col[e]], 1);
}

#define SCH 1024
__global__ __launch_bounds__(256) void k_bsum(const int* __restrict__ deg,
                                              int* __restrict__ bsum, int N) {
  __shared__ int ws[4];
  int tid = threadIdx.x;
  int base = blockIdx.x * SCH;
  int v = 0;
  #pragma unroll
  for (int k = 0; k < 4; k++) {
    int i = base + k * 256 + tid;
    if (i < N) v += deg[i];
  }
  #pragma unroll
  for (int s = 32; s; s >>= 1) v += __shfl_xor(v, s);
  if ((tid & 63) == 0) ws[tid >> 6] = v;
  __syncthreads();
  if (tid == 0) bsum[blockIdx.x] = ws[0] + ws[1] + ws[2] + ws[3];
}

__global__ __launch_bounds__(64) void k_bscan(const int* __restrict__ bsum,
                                              int* __restrict__ boff,
                                              int* __restrict__ off, int NB, int N) {
  int lane = threadIdx.x;
  int carry = 0;
  for (int base = 0; base < NB; base += 64) {
    int i = base + lane;
    int v = (i < NB) ? bsum[i] : 0;
    int sc = v;
    #pragma unroll
    for (int s = 1; s < 64; s <<= 1) {
      int t = __shfl_up(sc, s);
      if (lane >= s) sc += t;
    }
    if (i < NB) boff[i] = carry + sc - v;
    carry += __shfl(sc, 63);
  }
  if (lane == 0) off[N] = carry;
}

__global__ __launch_bounds__(256) void k_scan2(const int* __restrict__ deg,
                                               const int* __restrict__ boff,
                                               int* __restrict__ off,
                                               int* __restrict__ cur, int N) {
  __shared__ int wtot[4];
  int tid = threadIdx.x;
  int lane = tid & 63;
  int base = blockIdx.x * SCH + tid * 4;
  int v[4];
  #pragma unroll
  for (int k = 0; k < 4; k++) v[k] = (base + k < N) ? deg[base + k] : 0;
  int tsum = v[0] + v[1] + v[2] + v[3];
  int sc = tsum;
  #pragma unroll
  for (int s = 1; s < 64; s <<= 1) {
    int t = __shfl_up(sc, s);
    if (lane >= s) sc += t;
  }
  if (lane == 63) wtot[tid >> 6] = sc;
  __syncthreads();
  int w = tid >> 6;
  int woff = 0;
  if (w > 0) woff += wtot[0];
  if (w > 1) woff += wtot[1];
  if (w > 2) woff += wtot[2];
  int pre = boff[blockIdx.x] + woff + sc - tsum;
  #pragma unroll
  for (int k = 0; k < 4; k++) {
    int i = base + k;
    if (i < N) { off[i] = pre; cur[i] = pre; }
    pre += v[k];
  }
}

__global__ void k_scatter(const int* __restrict__ row, const int* __restrict__ col,
                          int* __restrict__ cur, int* __restrict__ csr_row, int E) {
  int e = blockIdx.x * blockDim.x + threadIdx.x;
  if (e < E) {
    int p = atomicAdd(&cur[col[e]], 1);
    csr_row[p] = row[e];
  }
}

// ---------------------------------------------------------------------------
// K6: fused 3-iteration routing + squash + exp_map.
// One wave per node. u gathered once into registers g[CAP]; transposed copy
// in LDS su_t[w*33+e] (conflict-free in both write and dot-read layouts).
// Dot: lane-pair (e,h) scans 32 words via fdot2 with base+imm offsets.
// exp(b) redistributed via v_readlane (no LDS round-trip). Weighted sum
// from registers. One lgkmcnt fence per round.
// ---------------------------------------------------------------------------
#define CAP 32
__global__ __launch_bounds__(64, 4) void k_route(
    const __half* __restrict__ uh, const float* __restrict__ bias,
    const int* __restrict__ csr_off, const int* __restrict__ csr_row,
    float* __restrict__ bg_ws, float* __restrict__ out, int N) {
  __shared__ uint su_t[64 * 33];          // word w of edge e at [w*33+e]
  __shared__ __align__(16) uint ssw[64];  // s as half2 words
  int lane = threadIdx.x;
  int j = blockIdx.x;
  int o0 = csr_off[j];
  int deg = csr_off[j + 1] - o0;
  int d0 = lane * 2;

  if (deg == 0) {
    *(float2*)(out + (size_t)j * 128 + d0) =
        make_float2((lane == 0) ? 1.f : 0.f, 0.f);
    return;
  }

  float2 bia = *(const float2*)(bias + d0);
  float s0 = 0.f, s1 = 0.f;

  if (deg <= CAP) {
    const uint* uhw = (const uint*)uh;   // half2-word view, 64 words/row
    int myrow = (lane < deg) ? csr_row[o0 + lane] : 0;

    // ---- parallel gathers: independent dest regs, one round-trip ----
    uint g[CAP];
    #pragma unroll
    for (int i = 0; i < CAP; ++i)
      if (i < deg) {
        int rr = __builtin_amdgcn_readlane(myrow, i);
        g[i] = uhw[(((size_t)(uint)rr) << 6) + lane];
      }

    // ---- transpose-stage to LDS + round-0 register sum (c = 1/deg) ----
    float a0 = 0.f, a1 = 0.f;
    #pragma unroll
    for (int i = 0; i < CAP; ++i)
      if (i < deg) {
        su_t[lane * 33 + i] = g[i];
        float2 uf = __half22float2(*(const __half2*)&g[i]);
        a0 += uf.x; a1 += uf.y;
      }

    float invd = 1.f / (float)deg;
    s0 = a0 * invd + bia.x;
    s1 = a1 * invd + bia.y;
    {
      float ns = s0 * s0 + s1 * s1;
      #pragma unroll
      for (int s = 32; s; s >>= 1) ns += __shfl_xor(ns, s);
      float scale = (ns / (1.f + ns)) * rsqrtf(ns + 1e-9f);
      s0 *= scale; s1 *= scale;
    }

    int e = lane >> 1, h = lane & 1;
    const uint* sut_e = &su_t[e + h * 32 * 33];
    const uint* ssw_h = &ssw[h * 32];
    float b = 0.f;

    #pragma unroll
    for (int r = 0; r < 2; ++r) {
      // publish s (f16)
      __half2 sh2 = __floats2half2_rn(s0, s1);
      ssw[lane] = *(const uint*)&sh2;
      LGKM_FENCE();

      // per-edge dot: 32 conflict-free b32 reads + 16 broadcast b64 reads
      float acc = 0.f;
      #pragma unroll
      for (int ww = 0; ww < 16; ++ww) {
        uint2 sw = *(const uint2*)&ssw_h[ww * 2];
        uint u0 = sut_e[(ww * 2) * 33];
        uint u1 = sut_e[(ww * 2 + 1) * 33];
        acc = dot2acc(u0, sw.x, acc);
        acc = dot2acc(u1, sw.y, acc);
      }
      acc += __shfl_xor(acc, 1);
      b += acc;
      float eb = __expf(b);

      // weighted sum from registers; exp via readlane broadcast
      float z = 0.f, w0 = 0.f, w1 = 0.f;
      #pragma unroll
      for (int i = 0; i < CAP; ++i)
        if (i < deg) {
          float ev = __uint_as_float(
              __builtin_amdgcn_readlane(__float_as_uint(eb), 2 * i));
          float2 uf = __half22float2(*(const __half2*)&g[i]);
          z += ev;
          w0 = fmaf(ev, uf.x, w0);
          w1 = fmaf(ev, uf.y, w1);
        }
      float invz = 1.f / z;
      s0 = w0 * invz + bia.x;
      s1 = w1 * invz + bia.y;
      float ns = s0 * s0 + s1 * s1;
      #pragma unroll
      for (int s = 32; s; s >>= 1) ns += __shfl_xor(ns, s);
      float scale = (ns / (1.f + ns)) * rsqrtf(ns + 1e-9f);
      s0 *= scale; s1 *= scale;
    }
  } else {
    // fallback (deg > CAP, ~never for Poisson(10)): global-b, per-wave only
    float* b = bg_ws + o0;
    const __half2* uh2 = (const __half2*)uh;
    for (int i = lane; i < deg; i += 64) atomicExch(&b[i], 0.f);
    asm volatile("s_waitcnt vmcnt(0)" ::: "memory");

    for (int r = 0; r < 3; ++r) {
      float mx = -3.4e38f;
      for (int i = lane; i < deg; i += 64)
        mx = fmaxf(mx, atomicAdd(&b[i], 0.f));
      #pragma unroll
      for (int s = 32; s; s >>= 1) mx = fmaxf(mx, __shfl_xor(mx, s));
      float z = 0.f;
      for (int i = lane; i < deg; i += 64) z += expf(atomicAdd(&b[i], 0.f) - mx);
      #pragma unroll
      for (int s = 32; s; s >>= 1) z += __shfl_xor(z, s);
      float invz = 1.f / z;

      s0 = 0.f; s1 = 0.f;
      for (int i = 0; i < deg; ++i) {
        float c = expf(atomicAdd(&b[i], 0.f) - mx) * invz;
        int rr = csr_row[o0 + i];
        float2 uf = __half22float2(uh2[(((size_t)rr) << 6) + lane]);
        s0 = fmaf(c, uf.x, s0);
        s1 = fmaf(c, uf.y, s1);
      }
      s0 += bia.x; s1 += bia.y;

      float ns = s0 * s0 + s1 * s1;
      #pragma unroll
      for (int s = 32; s; s >>= 1) ns += __shfl_xor(ns, s);
      float scale = (ns / (1.f + ns)) * rsqrtf(ns + 1e-9f);
      s0 *= scale; s1 *= scale;

      if (r < 2) {
        for (int i = 0; i < deg; ++i) {
          int rr = csr_row[o0 + i];
          float2 uf = __half22float2(uh2[(((size_t)rr) << 6) + lane]);
          float pp = s0 * uf.x + s1 * uf.y;
          #pragma unroll
          for (int s = 32; s; s >>= 1) pp += __shfl_xor(pp, s);
          if (lane == 0) atomicAdd(&b[i], pp);
        }
        asm volatile("s_waitcnt vmcnt(0)" ::: "memory");
      }
    }
  }

  // exp_map(s, ref)
  float pn = s0 * s0 + s1 * s1;
  if (lane == 0) pn -= 2.f * s0 * s0;
  #pragma unroll
  for (int s = 32; s; s >>= 1) pn += __shfl_xor(pn, s);
  float vn = fminf(sqrtf(fabsf(pn) + 1e-12f), 10.f);
  float sh = sinhf(vn) / vn;
  float ov0 = sh * s0 + ((lane == 0) ? coshf(vn) : 0.f);
  float ov1 = sh * s1;
  *(float2*)(out + (size_t)j * 128 + d0) = make_float2(ov0, ov1);
}

// ---------------------------------------------------------------------------
extern "C" void kernel_launch(void* const* d_in, const int* in_sizes, int n_in,
                              void* d_out, int out_size, void* d_ws, size_t ws_size,
                              hipStream_t stream) {
  const float* x    = (const float*)d_in[0];
  const int*   ei   = (const int*)d_in[1];
  const float* Wp   = (const float*)d_in[2];
  const float* bp   = (const float*)d_in[3];
  const float* Wg   = (const float*)d_in[4];
  const float* bg   = (const float*)d_in[5];
  const float* bias = (const float*)d_in[6];
  float* out = (float*)d_out;

  int N = in_sizes[0] / 128;
  int E = in_sizes[1] / 2;
  const int* row = ei;
  const int* col = ei + E;
  int NB = (N + SCH - 1) / SCH;

  __hip_bfloat16* xtb = (__hip_bfloat16*)d_ws;                  // N*128 bf16
  __half* uhh = (__half*)(xtb + (size_t)N * 128);               // N*128 f16
  float* gate = (float*)(uhh + (size_t)N * 128);                // N*4 f32
  __hip_bfloat16* Wt = (__hip_bfloat16*)(gate + (size_t)N * 4); // 512*128 bf16
  float* bws = (float*)(Wt + 512 * 128);                        // E f32
  int* deg = (int*)(bws + E);
  int* off = deg + N;
  int* cur = off + N + 1;
  int* csr_row = cur + N;
  int* bsum = csr_row + E;
  int* boff = bsum + NB;

  int tb = (N + 3) / 4;
  (void)hipMemsetAsync(deg, 0, (size_t)N * sizeof(int), stream);
  k_tangent_gate<<<tb + 256, 256, 0, stream>>>(x, Wg, bg, xtb, gate, Wp, Wt, N);
  k_uhat_mfma<<<(N + BM - 1) / BM, 256, 0, stream>>>(
      (const short*)xtb, gate, (const short*)Wt, bp, uhh, N);
  k_hist<<<(E + 255) / 256, 256, 0, stream>>>(col, deg, E);
  k_bsum<<<NB, 256, 0, stream>>>(deg, bsum, N);
  k_bscan<<<1, 64, 0, stream>>>(bsum, boff, off, NB, N);
  k_scan2<<<NB, 256, 0, stream>>>(deg, boff, off, cur, N);
  k_scatter<<<(E + 255) / 256, 256, 0, stream>>>(row, col, cur, csr_row, E);
  k_route<<<N, 64, 0, stream>>>(uhh, bias, off, csr_row, bws, out, N);
}